// Round 8
// baseline (267.251 us; speedup 1.0000x reference)
//
#include <hip/hip_runtime.h>

#define NN 50000
#define NE 800000
#define NG 64
#define D 128
#define DP 256
#define BN_EPS 1e-5f
#define NSLOT 32
#define NB 196   // ceil(NN/256)
#define NEB 3125 // NE/256 exactly

typedef unsigned short bf16;
typedef __attribute__((ext_vector_type(8))) short s16x8;
typedef __attribute__((ext_vector_type(4))) float f32x4;

__device__ __forceinline__ float bf2f(unsigned h16) {
  unsigned u = (h16 & 0xffffu) << 16; float f; __builtin_memcpy(&f, &u, 4); return f;
}
__device__ __forceinline__ bf16 f2bf(float f) {
  unsigned u; __builtin_memcpy(&u, &f, 4);
  return (bf16)((u + 0x7FFFu + ((u >> 16) & 1u)) >> 16);
}
__device__ __forceinline__ unsigned packbf2(float a, float b) {
  return (unsigned)f2bf(a) | ((unsigned)f2bf(b) << 16);
}
__device__ __forceinline__ s16x8 u4cast(uint4 v) {
  s16x8 r; __builtin_memcpy(&r, &v, 16); return r;
}

struct CvtArgs {
  const void* s[12];
  float* d[12];
  int n[12];
};

// ---------- fused pre: deg (blocks 0..NEB-1) | cvt (NEB..NEB+191) | flag (last) ----------
__global__ __launch_bounds__(256) void k_pre(const int* __restrict__ ei, int* __restrict__ cnt,
                                             CvtArgs a, const bf16* __restrict__ x,
                                             int* __restrict__ flag) {
  int b = blockIdx.x;
  if (b < NEB) {
    int e = b * 256 + threadIdx.x;
    atomicAdd(&cnt[ei[NE + e]], 1);
    return;
  }
  if (b < NEB + 192) {
    __shared__ int smode;
    if (threadIdx.x < 64) {
      float v = bf2f(x[2 * threadIdx.x]);
      float av = fabsf(v);
      int good = (v == 0.0f) || (av > 1e-30f && av < 32.0f);
      unsigned long long m = __ballot(good);
      if (threadIdx.x == 0) smode = (__popcll(m) >= 56) ? 1 : 0;
    }
    __syncthreads();
    int mode = smode;
    int idx = b - NEB;
    int t = idx >> 4;
    int base = (idx & 15) * 2048;
    int n = a.n[t];
    if (base >= n) return;
    float* dp = a.d[t];
    if (n >= 8) {
      int i8 = base + threadIdx.x * 8;
      if (i8 + 8 <= n) {
        if (mode) {
          uint4 raw = *(const uint4*)((const bf16*)a.s[t] + i8);
          *(float4*)(dp + i8) = make_float4(bf2f(raw.x & 0xffff), bf2f(raw.x >> 16),
                                            bf2f(raw.y & 0xffff), bf2f(raw.y >> 16));
          *(float4*)(dp + i8 + 4) = make_float4(bf2f(raw.z & 0xffff), bf2f(raw.z >> 16),
                                                bf2f(raw.w & 0xffff), bf2f(raw.w >> 16));
        } else {
          const float* s = (const float*)a.s[t] + i8;
          *(float4*)(dp + i8) = *(const float4*)s;
          *(float4*)(dp + i8 + 4) = *(const float4*)(s + 4);
        }
      }
    } else {
      int i = base + threadIdx.x;
      if (i < n) dp[i] = mode ? bf2f(((const bf16*)a.s[t])[i]) : ((const float*)a.s[t])[i];
    }
    return;
  }
  if (threadIdx.x < 64) {
    float v = bf2f(x[2 * threadIdx.x]);
    float av = fabsf(v);
    int good = (v == 0.0f) || (av > 1e-30f && av < 32.0f);
    unsigned long long m = __ballot(good);
    if (threadIdx.x == 0) { flag[0] = (__popcll(m) >= 56) ? 1 : 0; flag[1] = 1; }
  }
}

// ---------- W pack helper: MFMA B-frag layout ----------
__device__ __forceinline__ void pack_slot(const float* __restrict__ W, const float* __restrict__ scale,
                                          bf16* __restrict__ Wp, int slot) {
  int kc = slot >> 9, ct = (slot >> 6) & 7, l = slot & 63;
  int q = l >> 4, p = l & 15;
  int n = ct * 16 + p;
  unsigned u[4];
#pragma unroll
  for (int jj = 0; jj < 4; ++jj) {
    int k0 = kc * 32 + q * 8 + jj * 2;
    float w0 = W[k0 * D + n], w1 = W[(k0 + 1) * D + n];
    if (scale) { w0 *= scale[k0]; w1 *= scale[k0 + 1]; }
    u[jj] = packbf2(w0, w1);
  }
  *(uint4*)(Wp + (size_t)slot * 8) = make_uint4(u[0], u[1], u[2], u[3]);
}

__global__ __launch_bounds__(256) void k_pack(const float* __restrict__ W, const float* __restrict__ scale,
                                              bf16* __restrict__ Wp) {
  int slot = blockIdx.x * 256 + threadIdx.x;
  if (slot < 2048) pack_slot(W, scale, Wp, slot);
}

// ---------- fused scan: blocks <NB do scan+offsets+isq (atomic publish/spin); rest pack W1 ----------
__global__ __launch_bounds__(256) void k_scan3(const int* __restrict__ cnt,
                                               int* __restrict__ bsum, int* __restrict__ done,
                                               int* __restrict__ ro, int* __restrict__ cursor,
                                               float* __restrict__ isq,
                                               const float* __restrict__ W1f, bf16* __restrict__ Wpk1) {
  int b = blockIdx.x, t = threadIdx.x;
  if (b >= NB) {
    pack_slot(W1f, nullptr, Wpk1, (b - NB) * 256 + t);
    return;
  }
  __shared__ int sh[256];
  __shared__ int spart[4];
  __shared__ int sbase;
  int i = b * 256 + t;
  int c = (i < NN) ? cnt[i] : 0;
  sh[t] = c;
  __syncthreads();
  for (int off = 1; off < 256; off <<= 1) {
    int u = (t >= off) ? sh[t - off] : 0;
    __syncthreads();
    sh[t] += u;
    __syncthreads();
  }
  if (t == 255) {
    atomicExch(&bsum[b], sh[255]);
    __threadfence();
    atomicAdd(done, 1);
  }
  if (t == 0) {
    while (atomicAdd(done, 0) < NB) { __builtin_amdgcn_s_sleep(2); }
  }
  __syncthreads();
  int v = (t < b) ? atomicAdd(&bsum[t], 0) : 0;
  for (int off = 32; off; off >>= 1) v += __shfl_down(v, off);
  if ((t & 63) == 0) spart[t >> 6] = v;
  __syncthreads();
  if (t == 0) sbase = spart[0] + spart[1] + spart[2] + spart[3];
  __syncthreads();
  if (i < NN) {
    int o = sbase + sh[t] - c;
    ro[i] = o; cursor[i] = o;
    isq[i] = rsqrtf((float)(c + 1));
  }
  if (i == 0) ro[NN] = NE;
}

// ---------- fill CSR: pk[slot] = {src, bits(isq[s]*isq[d])} ----------
__global__ __launch_bounds__(256) void k_fill(const int* __restrict__ ei, const float* __restrict__ isq,
                                              int* __restrict__ cursor, int2* __restrict__ pk) {
  int e = blockIdx.x * 256 + threadIdx.x;
  if (e < NE) {
    int s = ei[e], d = ei[NE + e];
    int slot = atomicAdd(&cursor[d], 1);
    int2 v; v.x = s; v.y = __float_as_int(isq[s] * isq[d]);
    pk[slot] = v;
  }
}

// ---------- MFMA GEMM ----------
__global__ __launch_bounds__(256) void k_mgemm(const void* __restrict__ Xv, const int* __restrict__ flag,
                                               const bf16* __restrict__ Wp,
                                               const float* __restrict__ rowadd,
                                               bf16* __restrict__ Out, int nrows) {
  __shared__ float Cs[4][16][D + 4];
  int l = threadIdx.x & 63, w = threadIdx.x >> 6;
  int q = l >> 4, p = l & 15;
  int mode = flag ? flag[0] : 0;
  float rv[8];
#pragma unroll
  for (int ct = 0; ct < 8; ++ct) rv[ct] = rowadd ? rowadd[ct * 16 + p] : 0.f;
  int ntiles = (nrows + 63) >> 6;
  for (int t = blockIdx.x; t < ntiles; t += gridDim.x) {
    int wb = t * 64 + w * 16;
    int rowc = min(wb + p, nrows - 1);
    f32x4 acc[8];
#pragma unroll
    for (int ct = 0; ct < 8; ++ct) { f32x4 z = {rv[ct], rv[ct], rv[ct], rv[ct]}; acc[ct] = z; }
#pragma unroll
    for (int kc = 0; kc < 4; ++kc) {
      s16x8 a;
      if (mode) {
        uint4 av = *(const uint4*)((const bf16*)Xv + (size_t)rowc * D + kc * 32 + q * 8);
        a = u4cast(av);
      } else {
        const float* Xf = (const float*)Xv + (size_t)rowc * D + kc * 32 + q * 8;
        float4 f0 = *(const float4*)Xf;
        float4 f1 = *(const float4*)(Xf + 4);
        uint4 u = make_uint4(packbf2(f0.x, f0.y), packbf2(f0.z, f0.w),
                             packbf2(f1.x, f1.y), packbf2(f1.z, f1.w));
        a = u4cast(u);
      }
#pragma unroll
      for (int ct = 0; ct < 8; ++ct) {
        s16x8 bfr = *(const s16x8*)(Wp + (size_t)(((kc << 3) + ct) * 64 + l) * 8);
        acc[ct] = __builtin_amdgcn_mfma_f32_16x16x32_bf16(a, bfr, acc[ct], 0, 0, 0);
      }
    }
#pragma unroll
    for (int ct = 0; ct < 8; ++ct)
#pragma unroll
      for (int r = 0; r < 4; ++r)
        Cs[w][q * 4 + r][ct * 16 + p] = acc[ct][r];
    __syncthreads();
#pragma unroll
    for (int i = 0; i < 4; ++i) {
      int idx = i * 64 + l;
      int rr = idx >> 4, c8 = idx & 15;
      int gr = t * 64 + w * 16 + rr;
      if (gr < nrows) {
        float4 v0 = *(const float4*)&Cs[w][rr][c8 * 8];
        float4 v1 = *(const float4*)&Cs[w][rr][c8 * 8 + 4];
        uint4 o = make_uint4(packbf2(v0.x, v0.y), packbf2(v0.z, v0.w),
                             packbf2(v1.x, v1.y), packbf2(v1.z, v1.w));
        *(uint4*)(Out + (size_t)gr * D + c8 * 8) = o;
      }
    }
    __syncthreads();
  }
}

// ---------- CSR aggregation: dual-row gather (2 edges per VMEM instr, 8B/lane) ----------
template <int LAYER2>
__global__ __launch_bounds__(256, 4) void k_agg(const bf16* __restrict__ H, const int* __restrict__ ro,
                                                const int2* __restrict__ pk,
                                                const float* __restrict__ b, const int* __restrict__ batch,
                                                bf16* __restrict__ Rout,
                                                float* __restrict__ sumP, float* __restrict__ sumsqP,
                                                float* __restrict__ pooled) {
  int lane = threadIdx.x & 63;
  int w = __builtin_amdgcn_readfirstlane(threadIdx.x >> 6);
  int h = lane >> 5, c = lane & 31;   // half, col-group (4 bf16 cols per lane)
  int nbase = blockIdx.x * 16 + w * 4;
  float4 bv = ((const float4*)b)[c];
  float ls[4] = {0.f, 0.f, 0.f, 0.f}, lq[4] = {0.f, 0.f, 0.f, 0.f}, mx[4] = {0.f, 0.f, 0.f, 0.f};
  int gcur = -1;
  int nend = min(nbase + 4, NN);
  for (int n = nbase; n < nend; ++n) {
    int e0 = __builtin_amdgcn_readfirstlane(ro[n]);
    int e1 = __builtin_amdgcn_readfirstlane(ro[n + 1]);
    float invd = 1.0f / (float)(e1 - e0 + 1);
    uint2 hv = ((const uint2*)(H + (size_t)n * D))[c];
    float acc[4] = {0.f, 0.f, 0.f, 0.f};
    int e = e0;
    for (; e + 8 <= e1; e += 8) {
      int2 P[4]; uint2 X[4];
#pragma unroll
      for (int it = 0; it < 4; ++it) P[it] = pk[e + 2 * it + h];
#pragma unroll
      for (int it = 0; it < 4; ++it) X[it] = ((const uint2*)(H + (size_t)P[it].x * D))[c];
#pragma unroll
      for (int it = 0; it < 4; ++it) {
        float cc = __int_as_float(P[it].y);
        acc[0] += bf2f(X[it].x & 0xffff) * cc; acc[1] += bf2f(X[it].x >> 16) * cc;
        acc[2] += bf2f(X[it].y & 0xffff) * cc; acc[3] += bf2f(X[it].y >> 16) * cc;
      }
    }
    for (; e < e1; e += 2) {
      int eh = e + h;
      int2 p0 = (eh < e1) ? pk[eh] : make_int2(n, 0);
      uint2 X0 = ((const uint2*)(H + (size_t)p0.x * D))[c];
      float cc = __int_as_float(p0.y);
      acc[0] += bf2f(X0.x & 0xffff) * cc; acc[1] += bf2f(X0.x >> 16) * cc;
      acc[2] += bf2f(X0.y & 0xffff) * cc; acc[3] += bf2f(X0.y >> 16) * cc;
    }
#pragma unroll
    for (int j = 0; j < 4; ++j) acc[j] += __shfl_xor(acc[j], 32);
    float sf[4] = {bf2f(hv.x & 0xffff), bf2f(hv.x >> 16), bf2f(hv.y & 0xffff), bf2f(hv.y >> 16)};
    float bb[4] = {bv.x, bv.y, bv.z, bv.w};
    float r[4];
#pragma unroll
    for (int j = 0; j < 4; ++j) {
      r[j] = fmaxf(acc[j] + sf[j] * invd + bb[j], 0.f);
      ls[j] += r[j]; lq[j] += r[j] * r[j];
    }
    if (!LAYER2) {
      if (h == 0)
        ((uint2*)(Rout + (size_t)n * D))[c] = make_uint2(packbf2(r[0], r[1]), packbf2(r[2], r[3]));
    }
    if (LAYER2) {
      int g = batch[n];
      if (g != gcur) {
        if (gcur >= 0 && h == 0) {
#pragma unroll
          for (int j = 0; j < 4; ++j)
            atomicMax((int*)&pooled[(size_t)gcur * D + 4 * c + j], __float_as_int(mx[j]));
        }
        gcur = g;
#pragma unroll
        for (int j = 0; j < 4; ++j) mx[j] = 0.f;
      }
#pragma unroll
      for (int j = 0; j < 4; ++j) mx[j] = fmaxf(mx[j], r[j]);
    }
  }
  if (LAYER2 && gcur >= 0 && h == 0) {
#pragma unroll
    for (int j = 0; j < 4; ++j)
      atomicMax((int*)&pooled[(size_t)gcur * D + 4 * c + j], __float_as_int(mx[j]));
  }
  __shared__ float ss[4][D], sq[4][D];
  if (h == 0) {
#pragma unroll
    for (int j = 0; j < 4; ++j) { ss[w][4 * c + j] = ls[j]; sq[w][4 * c + j] = lq[j]; }
  }
  __syncthreads();
  int slot = (blockIdx.x & (NSLOT - 1)) * D;
  if (threadIdx.x < D) {
    int k = threadIdx.x;
    atomicAdd(&sumP[slot + k], ss[0][k] + ss[1][k] + ss[2][k] + ss[3][k]);
  } else {
    int k = threadIdx.x - D;
    atomicAdd(&sumsqP[slot + k], sq[0][k] + sq[1][k] + sq[2][k] + sq[3][k]);
  }
}

// ---------- BN1 stats + tW2 fold ----------
__global__ void k_bnstats1(const float* __restrict__ sumP, const float* __restrict__ sumsqP,
                           const float* __restrict__ gamma, const float* __restrict__ beta,
                           const float* __restrict__ W2,
                           float* __restrict__ svec, float* __restrict__ tW2) {
  __shared__ float t[D];
  int k = threadIdx.x;
  float sm = 0.f, sq = 0.f;
  for (int i = 0; i < NSLOT; ++i) { sm += sumP[i * D + k]; sq += sumsqP[i * D + k]; }
  float mean = sm * (1.0f / NN);
  float var = sq * (1.0f / NN) - mean * mean;
  float s = gamma[k] * rsqrtf(var + BN_EPS);
  svec[k] = s;
  t[k] = beta[k] - mean * s;
  __syncthreads();
  float acc = 0.f;
  for (int kk = 0; kk < D; ++kk) acc += t[kk] * W2[kk * D + k];
  tW2[k] = acc;
}

// ---------- head MLP (BN2 stats fused per block) ----------
__global__ __launch_bounds__(256) void k_head(const float* __restrict__ pooled,
                                              const float* __restrict__ sum2P, const float* __restrict__ sumsq2P,
                                              const float* __restrict__ gamma2, const float* __restrict__ beta2,
                                              const float* __restrict__ Wp1,
                                              const float* __restrict__ bp1, const float* __restrict__ Wp2,
                                              const float* __restrict__ bp2, void* out,
                                              const int* __restrict__ flag) {
  __shared__ float y[D];
  __shared__ float wr[4];
  int g = blockIdx.x, j = threadIdx.x;
  if (j < D) {
    float sm = 0.f, sq = 0.f;
    for (int i = 0; i < NSLOT; ++i) { sm += sum2P[i * D + j]; sq += sumsq2P[i * D + j]; }
    float mean = sm * (1.0f / NN);
    float var = sq * (1.0f / NN) - mean * mean;
    float s = gamma2[j] * rsqrtf(var + BN_EPS);
    y[j] = pooled[(size_t)g * D + j] * s + (beta2[j] - mean * s);
  }
  __syncthreads();
  float acc = bp1[j];
#pragma unroll 4
  for (int k = 0; k < D; ++k) acc += y[k] * Wp1[k * DP + j];
  float v = fmaxf(acc, 0.f) * Wp2[j];
  for (int off = 32; off; off >>= 1) v += __shfl_down(v, off);
  if ((j & 63) == 0) wr[j >> 6] = v;
  __syncthreads();
  if (j == 0) {
    float r = wr[0] + wr[1] + wr[2] + wr[3] + bp2[0];
    if (flag[0]) ((bf16*)out)[g] = f2bf(r);
    else ((float*)out)[g] = r;
  }
}

extern "C" void kernel_launch(void* const* d_in, const int* in_sizes, int n_in,
                              void* d_out, int out_size, void* d_ws, size_t ws_size,
                              hipStream_t stream) {
  const void* x   = d_in[0];
  const int*  ei  = (const int*)d_in[1];
  const int*  bat = (const int*)d_in[2];

  float* f = (float*)d_ws;
  bf16* A = (bf16*)f; f += (size_t)NN * D / 2;   // H1, then H2 (bf16)
  bf16* B = (bf16*)f; f += (size_t)NN * D / 2;   // R1 (bf16)
  // --- contiguous zero region ---
  float* zbase = f;
  int* cnt  = (int*)f; f += NN;
  int* done = (int*)f; f += 4;
  float* sum1P   = f; f += NSLOT * D;
  float* sumsq1P = f; f += NSLOT * D;
  float* sum2P   = f; f += NSLOT * D;
  float* sumsq2P = f; f += NSLOT * D;
  float* pooled  = f; f += (size_t)NG * D;
  size_t zbytes = (size_t)((char*)f - (char*)zbase);
  // --- rest ---
  float* W1f  = f; f += D * D;
  float* W2f  = f; f += D * D;
  float* Wp1f = f; f += D * DP;
  float* b1f  = f; f += D;
  float* g1f  = f; f += D;
  float* be1f = f; f += D;
  float* b2f  = f; f += D;
  float* g2f  = f; f += D;
  float* be2f = f; f += D;
  float* bp1f = f; f += DP;
  float* Wp2f = f; f += DP;
  float* bp2f = f; f += 4;
  bf16* Wpk1 = (bf16*)f; f += 2048 * 8 / 2;
  bf16* Wpk2 = (bf16*)f; f += 2048 * 8 / 2;
  float* svec1 = f; f += D;
  float* tW2   = f; f += D;
  float* isq   = f; f += NN;
  int2* pk    = (int2*)f; f += (size_t)NE * 2;
  int* ro     = (int*)f; f += NN + 1;
  int* cursor = (int*)f; f += NN;
  int* bsum   = (int*)f; f += NB;
  int* flag   = (int*)f;

  hipMemsetAsync(zbase, 0, zbytes, stream);

  CvtArgs ca;
  ca.s[0] = d_in[3];  ca.d[0] = W1f;  ca.n[0] = D * D;
  ca.s[1] = d_in[7];  ca.d[1] = W2f;  ca.n[1] = D * D;
  ca.s[2] = d_in[11]; ca.d[2] = Wp1f; ca.n[2] = D * DP;
  ca.s[3] = d_in[4];  ca.d[3] = b1f;  ca.n[3] = D;
  ca.s[4] = d_in[5];  ca.d[4] = g1f;  ca.n[4] = D;
  ca.s[5] = d_in[6];  ca.d[5] = be1f; ca.n[5] = D;
  ca.s[6] = d_in[8];  ca.d[6] = b2f;  ca.n[6] = D;
  ca.s[7] = d_in[9];  ca.d[7] = g2f;  ca.n[7] = D;
  ca.s[8] = d_in[10]; ca.d[8] = be2f; ca.n[8] = D;
  ca.s[9] = d_in[12]; ca.d[9] = bp1f; ca.n[9] = DP;
  ca.s[10] = d_in[13]; ca.d[10] = Wp2f; ca.n[10] = DP;
  ca.s[11] = d_in[14]; ca.d[11] = bp2f; ca.n[11] = 1;

  k_pre<<<NEB + 192 + 1, 256, 0, stream>>>(ei, cnt, ca, (const bf16*)x, flag);
  k_scan3<<<NB + 8, 256, 0, stream>>>(cnt, bsum, done, ro, cursor, isq, W1f, Wpk1);
  k_fill<<<NEB, 256, 0, stream>>>(ei, isq, cursor, pk);

  // layer 1
  k_mgemm<<<(NN + 63) / 64, 256, 0, stream>>>(x, flag, Wpk1, nullptr, A, NN);
  k_agg<0><<<(NN + 15) / 16, 256, 0, stream>>>(A, ro, pk, b1f, nullptr,
                                               B, sum1P, sumsq1P, nullptr);
  k_bnstats1<<<1, D, 0, stream>>>(sum1P, sumsq1P, g1f, be1f, W2f, svec1, tW2);

  // layer 2
  k_pack<<<8, 256, 0, stream>>>(W2f, svec1, Wpk2);
  k_mgemm<<<(NN + 63) / 64, 256, 0, stream>>>(B, flag + 1, Wpk2, tW2, A, NN);
  k_agg<1><<<(NN + 15) / 16, 256, 0, stream>>>(A, ro, pk, b2f, bat,
                                               nullptr, sum2P, sumsq2P, pooled);

  k_head<<<NG, DP, 0, stream>>>(pooled, sum2P, sumsq2P, g2f, be2f,
                                Wp1f, bp1f, Wp2f, bp2f, d_out, flag);
}

// Round 9
// 234.366 us; speedup vs baseline: 1.1403x; 1.1403x over previous
//
#include <hip/hip_runtime.h>

#define NN 50000
#define NE 800000
#define NG 64
#define D 128
#define DP 256
#define BN_EPS 1e-5f
#define NSLOT 32
#define NB 196   // ceil(NN/256)
#define NEB 3125 // NE/256 exactly

typedef unsigned short bf16;
typedef __attribute__((ext_vector_type(8))) short s16x8;
typedef __attribute__((ext_vector_type(4))) float f32x4;

__device__ __forceinline__ float bf2f(unsigned h16) {
  unsigned u = (h16 & 0xffffu) << 16; float f; __builtin_memcpy(&f, &u, 4); return f;
}
__device__ __forceinline__ bf16 f2bf(float f) {
  unsigned u; __builtin_memcpy(&u, &f, 4);
  return (bf16)((u + 0x7FFFu + ((u >> 16) & 1u)) >> 16);
}
__device__ __forceinline__ unsigned packbf2(float a, float b) {
  return (unsigned)f2bf(a) | ((unsigned)f2bf(b) << 16);
}
__device__ __forceinline__ s16x8 u4cast(uint4 v) {
  s16x8 r; __builtin_memcpy(&r, &v, 16); return r;
}

struct CvtArgs {
  const void* s[12];
  float* d[12];
  int n[12];
};

// ---------- fused pre: deg (blocks 0..NEB-1) | cvt (NEB..NEB+191) | flag (last) ----------
__global__ __launch_bounds__(256) void k_pre(const int* __restrict__ ei, int* __restrict__ cnt,
                                             CvtArgs a, const bf16* __restrict__ x,
                                             int* __restrict__ flag) {
  int b = blockIdx.x;
  if (b < NEB) {
    int e = b * 256 + threadIdx.x;
    atomicAdd(&cnt[ei[NE + e]], 1);
    return;
  }
  if (b < NEB + 192) {
    __shared__ int smode;
    if (threadIdx.x < 64) {
      float v = bf2f(x[2 * threadIdx.x]);
      float av = fabsf(v);
      int good = (v == 0.0f) || (av > 1e-30f && av < 32.0f);
      unsigned long long m = __ballot(good);
      if (threadIdx.x == 0) smode = (__popcll(m) >= 56) ? 1 : 0;
    }
    __syncthreads();
    int mode = smode;
    int idx = b - NEB;
    int t = idx >> 4;
    int base = (idx & 15) * 2048;
    int n = a.n[t];
    if (base >= n) return;
    float* dp = a.d[t];
    if (n >= 8) {
      int i8 = base + threadIdx.x * 8;
      if (i8 + 8 <= n) {
        if (mode) {
          uint4 raw = *(const uint4*)((const bf16*)a.s[t] + i8);
          *(float4*)(dp + i8) = make_float4(bf2f(raw.x & 0xffff), bf2f(raw.x >> 16),
                                            bf2f(raw.y & 0xffff), bf2f(raw.y >> 16));
          *(float4*)(dp + i8 + 4) = make_float4(bf2f(raw.z & 0xffff), bf2f(raw.z >> 16),
                                                bf2f(raw.w & 0xffff), bf2f(raw.w >> 16));
        } else {
          const float* s = (const float*)a.s[t] + i8;
          *(float4*)(dp + i8) = *(const float4*)s;
          *(float4*)(dp + i8 + 4) = *(const float4*)(s + 4);
        }
      }
    } else {
      int i = base + threadIdx.x;
      if (i < n) dp[i] = mode ? bf2f(((const bf16*)a.s[t])[i]) : ((const float*)a.s[t])[i];
    }
    return;
  }
  if (threadIdx.x < 64) {
    float v = bf2f(x[2 * threadIdx.x]);
    float av = fabsf(v);
    int good = (v == 0.0f) || (av > 1e-30f && av < 32.0f);
    unsigned long long m = __ballot(good);
    if (threadIdx.x == 0) { flag[0] = (__popcll(m) >= 56) ? 1 : 0; flag[1] = 1; }
  }
}

// ---------- W pack helper: MFMA B-frag layout ----------
__device__ __forceinline__ void pack_slot(const float* __restrict__ W, const float* __restrict__ scale,
                                          bf16* __restrict__ Wp, int slot) {
  int kc = slot >> 9, ct = (slot >> 6) & 7, l = slot & 63;
  int q = l >> 4, p = l & 15;
  int n = ct * 16 + p;
  unsigned u[4];
#pragma unroll
  for (int jj = 0; jj < 4; ++jj) {
    int k0 = kc * 32 + q * 8 + jj * 2;
    float w0 = W[k0 * D + n], w1 = W[(k0 + 1) * D + n];
    if (scale) { w0 *= scale[k0]; w1 *= scale[k0 + 1]; }
    u[jj] = packbf2(w0, w1);
  }
  *(uint4*)(Wp + (size_t)slot * 8) = make_uint4(u[0], u[1], u[2], u[3]);
}

__global__ __launch_bounds__(256) void k_pack(const float* __restrict__ W, const float* __restrict__ scale,
                                              bf16* __restrict__ Wp) {
  int slot = blockIdx.x * 256 + threadIdx.x;
  if (slot < 2048) pack_slot(W, scale, Wp, slot);
}

// ---------- fused scan: blocks <NB do scan+offsets+isq (atomic publish/spin); rest pack W1 ----------
__global__ __launch_bounds__(256) void k_scan3(const int* __restrict__ cnt,
                                               int* __restrict__ bsum, int* __restrict__ done,
                                               int* __restrict__ ro, int* __restrict__ cursor,
                                               float* __restrict__ isq,
                                               const float* __restrict__ W1f, bf16* __restrict__ Wpk1) {
  int b = blockIdx.x, t = threadIdx.x;
  if (b >= NB) {
    pack_slot(W1f, nullptr, Wpk1, (b - NB) * 256 + t);
    return;
  }
  __shared__ int sh[256];
  __shared__ int spart[4];
  __shared__ int sbase;
  int i = b * 256 + t;
  int c = (i < NN) ? cnt[i] : 0;
  sh[t] = c;
  __syncthreads();
  for (int off = 1; off < 256; off <<= 1) {
    int u = (t >= off) ? sh[t - off] : 0;
    __syncthreads();
    sh[t] += u;
    __syncthreads();
  }
  if (t == 255) {
    atomicExch(&bsum[b], sh[255]);
    __threadfence();
    atomicAdd(done, 1);
  }
  if (t == 0) {
    while (atomicAdd(done, 0) < NB) { __builtin_amdgcn_s_sleep(2); }
  }
  __syncthreads();
  int v = (t < b) ? atomicAdd(&bsum[t], 0) : 0;
  for (int off = 32; off; off >>= 1) v += __shfl_down(v, off);
  if ((t & 63) == 0) spart[t >> 6] = v;
  __syncthreads();
  if (t == 0) sbase = spart[0] + spart[1] + spart[2] + spart[3];
  __syncthreads();
  if (i < NN) {
    int o = sbase + sh[t] - c;
    ro[i] = o; cursor[i] = o;
    isq[i] = rsqrtf((float)(c + 1));
  }
  if (i == 0) ro[NN] = NE;
}

// ---------- fill CSR: pk[slot] = {src, bits(isq[s]*isq[d])} ----------
__global__ __launch_bounds__(256) void k_fill(const int* __restrict__ ei, const float* __restrict__ isq,
                                              int* __restrict__ cursor, int2* __restrict__ pk) {
  int e = blockIdx.x * 256 + threadIdx.x;
  if (e < NE) {
    int s = ei[e], d = ei[NE + e];
    int slot = atomicAdd(&cursor[d], 1);
    int2 v; v.x = s; v.y = __float_as_int(isq[s] * isq[d]);
    pk[slot] = v;
  }
}

// ---------- MFMA GEMM ----------
__global__ __launch_bounds__(256) void k_mgemm(const void* __restrict__ Xv, const int* __restrict__ flag,
                                               const bf16* __restrict__ Wp,
                                               const float* __restrict__ rowadd,
                                               bf16* __restrict__ Out, int nrows) {
  __shared__ float Cs[4][16][D + 4];
  int l = threadIdx.x & 63, w = threadIdx.x >> 6;
  int q = l >> 4, p = l & 15;
  int mode = flag ? flag[0] : 0;
  float rv[8];
#pragma unroll
  for (int ct = 0; ct < 8; ++ct) rv[ct] = rowadd ? rowadd[ct * 16 + p] : 0.f;
  int ntiles = (nrows + 63) >> 6;
  for (int t = blockIdx.x; t < ntiles; t += gridDim.x) {
    int wb = t * 64 + w * 16;
    int rowc = min(wb + p, nrows - 1);
    f32x4 acc[8];
#pragma unroll
    for (int ct = 0; ct < 8; ++ct) { f32x4 z = {rv[ct], rv[ct], rv[ct], rv[ct]}; acc[ct] = z; }
#pragma unroll
    for (int kc = 0; kc < 4; ++kc) {
      s16x8 a;
      if (mode) {
        uint4 av = *(const uint4*)((const bf16*)Xv + (size_t)rowc * D + kc * 32 + q * 8);
        a = u4cast(av);
      } else {
        const float* Xf = (const float*)Xv + (size_t)rowc * D + kc * 32 + q * 8;
        float4 f0 = *(const float4*)Xf;
        float4 f1 = *(const float4*)(Xf + 4);
        uint4 u = make_uint4(packbf2(f0.x, f0.y), packbf2(f0.z, f0.w),
                             packbf2(f1.x, f1.y), packbf2(f1.z, f1.w));
        a = u4cast(u);
      }
#pragma unroll
      for (int ct = 0; ct < 8; ++ct) {
        s16x8 bfr = *(const s16x8*)(Wp + (size_t)(((kc << 3) + ct) * 64 + l) * 8);
        acc[ct] = __builtin_amdgcn_mfma_f32_16x16x32_bf16(a, bfr, acc[ct], 0, 0, 0);
      }
    }
#pragma unroll
    for (int ct = 0; ct < 8; ++ct)
#pragma unroll
      for (int r = 0; r < 4; ++r)
        Cs[w][q * 4 + r][ct * 16 + p] = acc[ct][r];
    __syncthreads();
#pragma unroll
    for (int i = 0; i < 4; ++i) {
      int idx = i * 64 + l;
      int rr = idx >> 4, c8 = idx & 15;
      int gr = t * 64 + w * 16 + rr;
      if (gr < nrows) {
        float4 v0 = *(const float4*)&Cs[w][rr][c8 * 8];
        float4 v1 = *(const float4*)&Cs[w][rr][c8 * 8 + 4];
        uint4 o = make_uint4(packbf2(v0.x, v0.y), packbf2(v0.z, v0.w),
                             packbf2(v1.x, v1.y), packbf2(v1.z, v1.w));
        *(uint4*)(Out + (size_t)gr * D + c8 * 8) = o;
      }
    }
    __syncthreads();
  }
}

// ---------- CSR aggregation + fused epilogue (H bf16) ----------
// Lean per-lane state (2 cols/lane); 8-deep edge unroll -> 8 gathers in flight.
template <int LAYER2>
__global__ __launch_bounds__(256) void k_agg(const bf16* __restrict__ H, const int* __restrict__ ro,
                                             const int2* __restrict__ pk,
                                             const float* __restrict__ b, const int* __restrict__ batch,
                                             bf16* __restrict__ Rout,
                                             float* __restrict__ sumP, float* __restrict__ sumsqP,
                                             float* __restrict__ pooled) {
  int lane = threadIdx.x & 63;
  int w = __builtin_amdgcn_readfirstlane(threadIdx.x >> 6);
  int nbase = blockIdx.x * 16 + w * 4;
  float2 bv = ((const float2*)b)[lane];
  float2 ls = make_float2(0.f, 0.f), lq = make_float2(0.f, 0.f);
  int gcur = -1; float2 mx = make_float2(0.f, 0.f);
  int nend = min(nbase + 4, NN);
  for (int n = nbase; n < nend; ++n) {
    int r0 = __builtin_amdgcn_readfirstlane(ro[n]);
    int r1 = __builtin_amdgcn_readfirstlane(ro[n + 1]);
    float invd = 1.0f / (float)(r1 - r0 + 1);
    unsigned hv = ((const unsigned*)(H + (size_t)n * D))[lane];
    float2 acc = make_float2(bf2f(hv & 0xffff) * invd, bf2f(hv >> 16) * invd);
    int e = r0;
    for (; e + 8 <= r1; e += 8) {
      int2 P[8];
      unsigned X[8];
#pragma unroll
      for (int j = 0; j < 8; ++j) P[j] = pk[e + j];
#pragma unroll
      for (int j = 0; j < 8; ++j) X[j] = ((const unsigned*)(H + (size_t)P[j].x * D))[lane];
#pragma unroll
      for (int j = 0; j < 8; ++j) {
        float c = __int_as_float(P[j].y);
        acc.x += bf2f(X[j] & 0xffff) * c; acc.y += bf2f(X[j] >> 16) * c;
      }
    }
    for (; e + 4 <= r1; e += 4) {
      int2 p0 = pk[e], p1 = pk[e + 1], p2 = pk[e + 2], p3 = pk[e + 3];
      unsigned x0 = ((const unsigned*)(H + (size_t)p0.x * D))[lane];
      unsigned x1 = ((const unsigned*)(H + (size_t)p1.x * D))[lane];
      unsigned x2 = ((const unsigned*)(H + (size_t)p2.x * D))[lane];
      unsigned x3 = ((const unsigned*)(H + (size_t)p3.x * D))[lane];
      float c0 = __int_as_float(p0.y), c1 = __int_as_float(p1.y);
      float c2 = __int_as_float(p2.y), c3 = __int_as_float(p3.y);
      acc.x += bf2f(x0 & 0xffff) * c0; acc.y += bf2f(x0 >> 16) * c0;
      acc.x += bf2f(x1 & 0xffff) * c1; acc.y += bf2f(x1 >> 16) * c1;
      acc.x += bf2f(x2 & 0xffff) * c2; acc.y += bf2f(x2 >> 16) * c2;
      acc.x += bf2f(x3 & 0xffff) * c3; acc.y += bf2f(x3 >> 16) * c3;
    }
    for (; e < r1; ++e) {
      int2 p0 = pk[e];
      unsigned x0 = ((const unsigned*)(H + (size_t)p0.x * D))[lane];
      float c0 = __int_as_float(p0.y);
      acc.x += bf2f(x0 & 0xffff) * c0; acc.y += bf2f(x0 >> 16) * c0;
    }
    float2 r = make_float2(fmaxf(acc.x + bv.x, 0.f), fmaxf(acc.y + bv.y, 0.f));
    if (!LAYER2) ((unsigned*)(Rout + (size_t)n * D))[lane] = packbf2(r.x, r.y);
    ls.x += r.x; ls.y += r.y; lq.x += r.x * r.x; lq.y += r.y * r.y;
    if (LAYER2) {
      int g = batch[n];
      if (g != gcur) {
        if (gcur >= 0) {
          atomicMax((int*)&pooled[(size_t)gcur * D + 2 * lane], __float_as_int(mx.x));
          atomicMax((int*)&pooled[(size_t)gcur * D + 2 * lane + 1], __float_as_int(mx.y));
        }
        gcur = g; mx = make_float2(0.f, 0.f);
      }
      mx.x = fmaxf(mx.x, r.x); mx.y = fmaxf(mx.y, r.y);
    }
  }
  if (LAYER2 && gcur >= 0) {
    atomicMax((int*)&pooled[(size_t)gcur * D + 2 * lane], __float_as_int(mx.x));
    atomicMax((int*)&pooled[(size_t)gcur * D + 2 * lane + 1], __float_as_int(mx.y));
  }
  __shared__ float ss[4][D], sq[4][D];
  ss[w][2 * lane] = ls.x; ss[w][2 * lane + 1] = ls.y;
  sq[w][2 * lane] = lq.x; sq[w][2 * lane + 1] = lq.y;
  __syncthreads();
  int slot = (blockIdx.x & (NSLOT - 1)) * D;
  if (threadIdx.x < D) {
    int k = threadIdx.x;
    atomicAdd(&sumP[slot + k], ss[0][k] + ss[1][k] + ss[2][k] + ss[3][k]);
  } else {
    int k = threadIdx.x - D;
    atomicAdd(&sumsqP[slot + k], sq[0][k] + sq[1][k] + sq[2][k] + sq[3][k]);
  }
}

// ---------- BN1 stats + tW2 fold ----------
__global__ void k_bnstats1(const float* __restrict__ sumP, const float* __restrict__ sumsqP,
                           const float* __restrict__ gamma, const float* __restrict__ beta,
                           const float* __restrict__ W2,
                           float* __restrict__ svec, float* __restrict__ tW2) {
  __shared__ float t[D];
  int k = threadIdx.x;
  float sm = 0.f, sq = 0.f;
  for (int i = 0; i < NSLOT; ++i) { sm += sumP[i * D + k]; sq += sumsqP[i * D + k]; }
  float mean = sm * (1.0f / NN);
  float var = sq * (1.0f / NN) - mean * mean;
  float s = gamma[k] * rsqrtf(var + BN_EPS);
  svec[k] = s;
  t[k] = beta[k] - mean * s;
  __syncthreads();
  float acc = 0.f;
  for (int kk = 0; kk < D; ++kk) acc += t[kk] * W2[kk * D + k];
  tW2[k] = acc;
}

// ---------- head MLP (BN2 stats fused per block) ----------
__global__ __launch_bounds__(256) void k_head(const float* __restrict__ pooled,
                                              const float* __restrict__ sum2P, const float* __restrict__ sumsq2P,
                                              const float* __restrict__ gamma2, const float* __restrict__ beta2,
                                              const float* __restrict__ Wp1,
                                              const float* __restrict__ bp1, const float* __restrict__ Wp2,
                                              const float* __restrict__ bp2, void* out,
                                              const int* __restrict__ flag) {
  __shared__ float y[D];
  __shared__ float wr[4];
  int g = blockIdx.x, j = threadIdx.x;
  if (j < D) {
    float sm = 0.f, sq = 0.f;
    for (int i = 0; i < NSLOT; ++i) { sm += sum2P[i * D + j]; sq += sumsq2P[i * D + j]; }
    float mean = sm * (1.0f / NN);
    float var = sq * (1.0f / NN) - mean * mean;
    float s = gamma2[j] * rsqrtf(var + BN_EPS);
    y[j] = pooled[(size_t)g * D + j] * s + (beta2[j] - mean * s);
  }
  __syncthreads();
  float acc = bp1[j];
#pragma unroll 4
  for (int k = 0; k < D; ++k) acc += y[k] * Wp1[k * DP + j];
  float v = fmaxf(acc, 0.f) * Wp2[j];
  for (int off = 32; off; off >>= 1) v += __shfl_down(v, off);
  if ((j & 63) == 0) wr[j >> 6] = v;
  __syncthreads();
  if (j == 0) {
    float r = wr[0] + wr[1] + wr[2] + wr[3] + bp2[0];
    if (flag[0]) ((bf16*)out)[g] = f2bf(r);
    else ((float*)out)[g] = r;
  }
}

extern "C" void kernel_launch(void* const* d_in, const int* in_sizes, int n_in,
                              void* d_out, int out_size, void* d_ws, size_t ws_size,
                              hipStream_t stream) {
  const void* x   = d_in[0];
  const int*  ei  = (const int*)d_in[1];
  const int*  bat = (const int*)d_in[2];

  float* f = (float*)d_ws;
  bf16* A = (bf16*)f; f += (size_t)NN * D / 2;   // H1, then H2 (bf16)
  bf16* B = (bf16*)f; f += (size_t)NN * D / 2;   // R1 (bf16)
  // --- contiguous zero region ---
  float* zbase = f;
  int* cnt  = (int*)f; f += NN;
  int* done = (int*)f; f += 4;
  float* sum1P   = f; f += NSLOT * D;
  float* sumsq1P = f; f += NSLOT * D;
  float* sum2P   = f; f += NSLOT * D;
  float* sumsq2P = f; f += NSLOT * D;
  float* pooled  = f; f += (size_t)NG * D;
  size_t zbytes = (size_t)((char*)f - (char*)zbase);
  // --- rest ---
  float* W1f  = f; f += D * D;
  float* W2f  = f; f += D * D;
  float* Wp1f = f; f += D * DP;
  float* b1f  = f; f += D;
  float* g1f  = f; f += D;
  float* be1f = f; f += D;
  float* b2f  = f; f += D;
  float* g2f  = f; f += D;
  float* be2f = f; f += D;
  float* bp1f = f; f += DP;
  float* Wp2f = f; f += DP;
  float* bp2f = f; f += 4;
  bf16* Wpk1 = (bf16*)f; f += 2048 * 8 / 2;
  bf16* Wpk2 = (bf16*)f; f += 2048 * 8 / 2;
  float* svec1 = f; f += D;
  float* tW2   = f; f += D;
  float* isq   = f; f += NN;
  int2* pk    = (int2*)f; f += (size_t)NE * 2;
  int* ro     = (int*)f; f += NN + 1;
  int* cursor = (int*)f; f += NN;
  int* bsum   = (int*)f; f += NB;
  int* flag   = (int*)f;

  hipMemsetAsync(zbase, 0, zbytes, stream);

  CvtArgs ca;
  ca.s[0] = d_in[3];  ca.d[0] = W1f;  ca.n[0] = D * D;
  ca.s[1] = d_in[7];  ca.d[1] = W2f;  ca.n[1] = D * D;
  ca.s[2] = d_in[11]; ca.d[2] = Wp1f; ca.n[2] = D * DP;
  ca.s[3] = d_in[4];  ca.d[3] = b1f;  ca.n[3] = D;
  ca.s[4] = d_in[5];  ca.d[4] = g1f;  ca.n[4] = D;
  ca.s[5] = d_in[6];  ca.d[5] = be1f; ca.n[5] = D;
  ca.s[6] = d_in[8];  ca.d[6] = b2f;  ca.n[6] = D;
  ca.s[7] = d_in[9];  ca.d[7] = g2f;  ca.n[7] = D;
  ca.s[8] = d_in[10]; ca.d[8] = be2f; ca.n[8] = D;
  ca.s[9] = d_in[12]; ca.d[9] = bp1f; ca.n[9] = DP;
  ca.s[10] = d_in[13]; ca.d[10] = Wp2f; ca.n[10] = DP;
  ca.s[11] = d_in[14]; ca.d[11] = bp2f; ca.n[11] = 1;

  k_pre<<<NEB + 192 + 1, 256, 0, stream>>>(ei, cnt, ca, (const bf16*)x, flag);
  k_scan3<<<NB + 8, 256, 0, stream>>>(cnt, bsum, done, ro, cursor, isq, W1f, Wpk1);
  k_fill<<<NEB, 256, 0, stream>>>(ei, isq, cursor, pk);

  // layer 1
  k_mgemm<<<(NN + 63) / 64, 256, 0, stream>>>(x, flag, Wpk1, nullptr, A, NN);
  k_agg<0><<<(NN + 15) / 16, 256, 0, stream>>>(A, ro, pk, b1f, nullptr,
                                               B, sum1P, sumsq1P, nullptr);
  k_bnstats1<<<1, D, 0, stream>>>(sum1P, sumsq1P, g1f, be1f, W2f, svec1, tW2);

  // layer 2
  k_pack<<<8, 256, 0, stream>>>(W2f, svec1, Wpk2);
  k_mgemm<<<(NN + 63) / 64, 256, 0, stream>>>(B, flag + 1, Wpk2, tW2, A, NN);
  k_agg<1><<<(NN + 15) / 16, 256, 0, stream>>>(A, ro, pk, b2f, bat,
                                               nullptr, sum2P, sumsq2P, pooled);

  k_head<<<NG, DP, 0, stream>>>(pooled, sum2P, sumsq2P, g2f, be2f,
                                Wp1f, bp1f, Wp2f, bp2f, d_out, flag);
}